// Round 3
// baseline (124.329 us; speedup 1.0000x reference)
//
#include <hip/hip_runtime.h>
#include <stdint.h>

#define NV 8192   // vision rows
#define MT 8192   // text rows
#define DD 128    // feature dim
#define KB 768    // BERT dim

typedef __attribute__((ext_vector_type(8))) short short8;
typedef __attribute__((ext_vector_type(4))) float f32x4;

__device__ __forceinline__ ushort f2bf(float f) {
  uint32_t u = __float_as_uint(f);
  u += 0x7FFF + ((u >> 16) & 1);   // round-to-nearest-even
  return (ushort)(u >> 16);
}

// ---------------- Kernel 1: vision row-normalize -> bf16 ----------------
__global__ __launch_bounds__(256) void k_visnorm(const float* __restrict__ vis,
                                                 ushort* __restrict__ vn) {
  const int tx = threadIdx.x & 15;
  const int r  = blockIdx.x * 16 + (threadIdx.x >> 4);
  const float* p = vis + (size_t)r * DD + tx * 8;
  float4 a = *(const float4*)p;
  float4 b = *(const float4*)(p + 4);
  float s = a.x*a.x + a.y*a.y + a.z*a.z + a.w*a.w
          + b.x*b.x + b.y*b.y + b.z*b.z + b.w*b.w;
  s += __shfl_xor(s, 1, 16);
  s += __shfl_xor(s, 2, 16);
  s += __shfl_xor(s, 4, 16);
  s += __shfl_xor(s, 8, 16);
  const float inv = 1.0f / fmaxf(sqrtf(s), 1e-8f);
  union { ushort u[8]; uint4 v; } o;
  o.u[0] = f2bf(a.x * inv); o.u[1] = f2bf(a.y * inv);
  o.u[2] = f2bf(a.z * inv); o.u[3] = f2bf(a.w * inv);
  o.u[4] = f2bf(b.x * inv); o.u[5] = f2bf(b.y * inv);
  o.u[6] = f2bf(b.z * inv); o.u[7] = f2bf(b.w * inv);
  *(uint4*)(vn + (size_t)r * DD + tx * 8) = o.v;
}

// ---------------- Kernel 2: f32 -> bf16 bulk convert ---------------------
__global__ __launch_bounds__(256) void k_cvt(const float* __restrict__ src,
                                             ushort* __restrict__ dst) {
  const size_t i = ((size_t)blockIdx.x * 256 + threadIdx.x) * 8;
  float4 a = *(const float4*)(src + i);
  float4 b = *(const float4*)(src + i + 4);
  union { ushort u[8]; uint4 v; } o;
  o.u[0] = f2bf(a.x); o.u[1] = f2bf(a.y); o.u[2] = f2bf(a.z); o.u[3] = f2bf(a.w);
  o.u[4] = f2bf(b.x); o.u[5] = f2bf(b.y); o.u[6] = f2bf(b.z); o.u[7] = f2bf(b.w);
  *(uint4*)(dst + i) = o.v;
}

// ---------------- Kernel 3: projection MFMA + bias + normalize -> bf16 ---
// 1 wave/block, 512 blocks; wave computes 16 text rows x all 128 dims,
// then bias + row-norm in-register from the accumulator.
__global__ __launch_bounds__(64) void k_projnorm(const ushort* __restrict__ tb,
                                                 const ushort* __restrict__ wb,
                                                 const float* __restrict__ bias,
                                                 ushort* __restrict__ tn) {
  const int lane = threadIdx.x;
  const int row0 = blockIdx.x * 16;
  const int lrow = lane & 15;
  const int g    = lane >> 4;        // 0..3
  const int koff = g * 8;

  const ushort* ap = tb + (size_t)(row0 + lrow) * KB + koff;
  const ushort* bp = wb + (size_t)lrow * KB + koff;

  f32x4 acc[8] = {};

#pragma unroll 4
  for (int ks = 0; ks < KB / 32; ++ks) {
    short8 a = *(const short8*)(ap + ks * 32);
#pragma unroll
    for (int n = 0; n < 8; ++n) {
      short8 b = *(const short8*)(bp + (size_t)n * 16 * KB + ks * 32);
      acc[n] = __builtin_amdgcn_mfma_f32_16x16x32_bf16(a, b, acc[n], 0, 0, 0);
    }
  }

  // D layout: row = g*4 + j (j=reg), col = n*16 + (lane&15)
  // bias add
#pragma unroll
  for (int n = 0; n < 8; ++n) {
    float bv = bias[n * 16 + lrow];
#pragma unroll
    for (int j = 0; j < 4; ++j) acc[n][j] += bv;
  }
  // per-row sumsq: rows distinguished by j within this lane; reduce over
  // the 16 lanes (same g) holding different cols.
  float s0 = 0.f, s1 = 0.f, s2 = 0.f, s3 = 0.f;
#pragma unroll
  for (int n = 0; n < 8; ++n) {
    s0 += acc[n][0] * acc[n][0];
    s1 += acc[n][1] * acc[n][1];
    s2 += acc[n][2] * acc[n][2];
    s3 += acc[n][3] * acc[n][3];
  }
#pragma unroll
  for (int d = 1; d < 16; d <<= 1) {
    s0 += __shfl_xor(s0, d, 16);
    s1 += __shfl_xor(s1, d, 16);
    s2 += __shfl_xor(s2, d, 16);
    s3 += __shfl_xor(s3, d, 16);
  }
  float inv[4];
  inv[0] = 1.0f / fmaxf(sqrtf(s0), 1e-8f);
  inv[1] = 1.0f / fmaxf(sqrtf(s1), 1e-8f);
  inv[2] = 1.0f / fmaxf(sqrtf(s2), 1e-8f);
  inv[3] = 1.0f / fmaxf(sqrtf(s3), 1e-8f);

#pragma unroll
  for (int n = 0; n < 8; ++n)
#pragma unroll
    for (int j = 0; j < 4; ++j)
      tn[(size_t)(row0 + g * 4 + j) * DD + n * 16 + lrow] = f2bf(acc[n][j] * inv[j]);
}

// ---------------- Kernel 4: similarity GEMM (LDS-staged, swizzled) -------
// 4096 blocks (XCD-swizzled), 256 thr = 4 waves (2x2), tile 128x128, K=128.
// Stage A,B into LDS (reg-staged, T2 XOR swizzle), one MFMA pass, then
// LDS-transpose epilogue -> coalesced dwordx4 stores.
__global__ __launch_bounds__(256, 2) void k_sim(const ushort* __restrict__ vn,
                                                const ushort* __restrict__ tn,
                                                float* __restrict__ out) {
  __shared__ ushort ls[32768];           // 64 KB: A[16384] | B[16384], reused as f32
  ushort* lsA = ls;
  ushort* lsB = ls + 16384;
  float*  lsf = (float*)ls;

  // XCD swizzle: 4096 blocks, 8 XCDs, 512 consecutive per XCD
  const int lin  = blockIdx.x;
  const int nlin = (lin & 7) * 512 + (lin >> 3);
  const int by   = nlin >> 6;
  const int bx   = nlin & 63;
  const int row0 = by * 128;
  const int col0 = bx * 128;

  const int t    = threadIdx.x;
  const int lane = t & 63;
  const int wave = t >> 6;

  // ---- stage A and B: 8 x 16B per thread each, swizzled ds_write ----
#pragma unroll
  for (int i = 0; i < 8; ++i) {
    const int fi  = i * 256 + t;           // 16B unit index
    const int row = fi >> 4;               // 0..127
    uint4 va = *(const uint4*)(vn + (size_t)row0 * DD + fi * 8);
    uint4 vb = *(const uint4*)(tn + (size_t)col0 * DD + fi * 8);
    const int idx = (fi * 8) ^ ((row & 7) << 3);   // ushort index, 16B-aligned XOR
    *(uint4*)(lsA + idx) = va;
    *(uint4*)(lsB + idx) = vb;
  }
  __syncthreads();

  // ---- MFMA: wave (wr,wc) computes 64x64 at (wr*64, wc*64) ----
  const int wr = wave >> 1;
  const int wc = wave & 1;
  const int lrow = lane & 15;
  const int kgrp = lane >> 4;            // 0..3

  f32x4 acc[4][4] = {};

#pragma unroll
  for (int ks = 0; ks < 4; ++ks) {
    short8 a[4], b[4];
#pragma unroll
    for (int m = 0; m < 4; ++m) {
      const int r = wr * 64 + m * 16 + lrow;
      const int c = ks * 32 + kgrp * 8;
      a[m] = *(const short8*)(lsA + ((r * 128 + c) ^ ((r & 7) << 3)));
    }
#pragma unroll
    for (int n = 0; n < 4; ++n) {
      const int r = wc * 64 + n * 16 + lrow;
      const int c = ks * 32 + kgrp * 8;
      b[n] = *(const short8*)(lsB + ((r * 128 + c) ^ ((r & 7) << 3)));
    }
#pragma unroll
    for (int m = 0; m < 4; ++m)
#pragma unroll
      for (int n = 0; n < 4; ++n)
        acc[m][n] = __builtin_amdgcn_mfma_f32_16x16x32_bf16(a[m], b[n], acc[m][n], 0, 0, 0);
  }
  __syncthreads();   // A/B fragments consumed; LDS now reused as f32 tile

  // ---- write acc to LDS f32 tile (2-way-swizzled) ----
  // D layout: row = (lane>>4)*4 + j, col = lane&15 (within 16x16)
  const int orow = kgrp * 4;
#pragma unroll
  for (int m = 0; m < 4; ++m)
#pragma unroll
    for (int n = 0; n < 4; ++n) {
      const int r = wr * 64 + m * 16 + orow;
      const int c = wc * 64 + n * 16 + lrow;
#pragma unroll
      for (int j = 0; j < 4; ++j) {
        const int rr = r + j;
        lsf[(rr * 128 + c) ^ (((rr >> 2) & 1) << 4)] = acc[m][n][j];
      }
    }
  __syncthreads();

  // ---- coalesced f32 stores: 16 passes x (8 rows, 32 lanes x float4) ----
  const int cr = t >> 5;        // 0..7
  const int cc = (t & 31) * 4;  // 0..124
#pragma unroll
  for (int p = 0; p < 16; ++p) {
    const int r = p * 8 + cr;
    const int idx = (r * 128 + cc) ^ (((r >> 2) & 1) << 4);
    float4 v = *(const float4*)&lsf[idx];
    *(float4*)(out + (size_t)(row0 + r) * MT + col0 + cc) = v;
  }
}

extern "C" void kernel_launch(void* const* d_in, const int* in_sizes, int n_in,
                              void* d_out, int out_size, void* d_ws, size_t ws_size,
                              hipStream_t stream) {
  (void)in_sizes; (void)n_in; (void)out_size; (void)ws_size;
  const float* vis  = (const float*)d_in[0];  // [8192,128]
  const float* txt  = (const float*)d_in[1];  // [8192,768]
  const float* w    = (const float*)d_in[2];  // [128,768]
  const float* bias = (const float*)d_in[3];  // [128]
  float* out = (float*)d_out;                 // [8192,8192]

  // ws layout: vn 2MB @0 | tn 2MB @2MB | tb 12MB @4MB | wb 192KB @16MB
  char* ws = (char*)d_ws;
  ushort* vn = (ushort*)(ws);
  ushort* tn = (ushort*)(ws + (size_t)2097152);
  ushort* tb = (ushort*)(ws + (size_t)4194304);
  ushort* wb = (ushort*)(ws + (size_t)16777216);

  k_visnorm<<<NV / 16, 256, 0, stream>>>(vis, vn);
  k_cvt<<<(MT * KB) / 2048, 256, 0, stream>>>(txt, tb);
  k_cvt<<<(DD * KB) / 2048, 256, 0, stream>>>(w, wb);
  k_projnorm<<<MT / 16, 64, 0, stream>>>(tb, wb, bias, tn);
  k_sim<<<4096, 256, 0, stream>>>(vn, tn, out);
}